// Round 7
// baseline (258.291 us; speedup 1.0000x reference)
//
#include <hip/hip_runtime.h>

// Round-12: polished two-kernel segment scan, fully linear DRAM traversal.
// Round-11 post-mortem: per-instruction-contiguous footprint (256 B/instr)
// still capped at 2.4 TB/s with ideal traffic -> the cap is the wave's
// TEMPORAL address stream (4 KB stride down H = DRAM row-activate bound),
// not the per-instruction footprint. Fill (linear) = 6.6 TB/s on the same
// machine. Every column-ownership kernel walks strided; only the segment
// scan streams linearly, and every sync primitive measured is ruinous
// (flags 320 us, coop grid.sync 201 us) -> two plain launches.
//   A: block (b,s) streams its 32-row band (128 KB CONTIGUOUS) with
//      double-buffered 8-row batches, column-max -> agg[b][s][:] (4 KB).
//   B: carry = max over agg[b][k<s] (<=124 KB, L3; only k<s batches read),
//      then re-stream own band (L3-resident: A just traversed all of x,
//      256 MB L3 holds it within the iteration) scan+store, linear writes.
// HBM traffic: x once (~134 MB) + out (~134 MB) + agg 2x4 MB.
// Decision metric: bench dur_us (kernels likely < fill's 78 us -> absent
// from top-5 counter table). Falsifier: A+B >= 85 us => r11 (83 us) is the
// practical cap; restore it and declare roofline.

constexpr int B = 32;
constexpr int H = 1024;
constexpr int W = 1024;
constexpr int ROW4 = W / 4;        // 256 float4 per row = 4 KB
constexpr int NSEG = 32;           // bands along H
constexpr int SH = H / NSEG;       // 32 rows per band
constexpr int NB = B * NSEG;       // 1024 blocks
constexpr size_t AGG_BYTES = (size_t)NB * ROW4 * sizeof(float4);  // 4 MiB

__device__ __forceinline__ float4 max4(float4 a, float4 b) {
    return make_float4(fmaxf(a.x, b.x), fmaxf(a.y, b.y),
                       fmaxf(a.z, b.z), fmaxf(a.w, b.w));
}

// ---------------- pass A: per-(b,band) column max, linear stream ----------
__global__ __launch_bounds__(256) void band_colmax(const float* __restrict__ xf,
                                                   float* __restrict__ tf) {
    const int id = blockIdx.x;
    const int b = id >> 5;
    const int s = id & (NSEG - 1);
    const int t = threadIdx.x;         // float4-column: 256 threads = 4 KB row
    const float4* x4 = (const float4*)xf;
    float4* t4 = (float4*)tf;

    const size_t base = ((size_t)b * H + (size_t)s * SH) * ROW4 + t;

    float4 cur[8], nxt[8];
#pragma unroll
    for (int r = 0; r < 8; ++r) cur[r] = x4[base + (size_t)r * ROW4];

    const float ninf = -__builtin_inff();
    float4 m = make_float4(ninf, ninf, ninf, ninf);

#pragma unroll
    for (int g = 0; g < SH; g += 8) {
        if (g + 8 < SH) {
#pragma unroll
            for (int r = 0; r < 8; ++r)
                nxt[r] = x4[base + (size_t)(g + 8 + r) * ROW4];
        }
#pragma unroll
        for (int r = 0; r < 8; ++r) m = max4(m, cur[r]);
        if (g + 8 < SH) {
#pragma unroll
            for (int r = 0; r < 8; ++r) cur[r] = nxt[r];
        }
    }
    t4[(size_t)id * ROW4 + t] = m;
}

// ------------- pass B: lookback carry + linear scan of own band -----------
__global__ __launch_bounds__(256) void band_apply(const float* __restrict__ xf,
                                                  const float* __restrict__ tf,
                                                  float* __restrict__ of) {
    const int id = blockIdx.x;
    const int b = id >> 5;
    const int s = id & (NSEG - 1);
    const int t = threadIdx.x;
    const float4* x4 = (const float4*)xf;
    const float4* t4 = (const float4*)tf;
    float4* o4 = (float4*)of;

    const float ninf = -__builtin_inff();
    float4 carry = make_float4(ninf, ninf, ninf, ninf);

    // lookback over predecessor bands only (k < s); batches of 8,
    // loads always in-bounds (g <= 24, g+k <= 31)
    for (int g = 0; g < s; g += 8) {
        float4 v[8];
#pragma unroll
        for (int k = 0; k < 8; ++k)
            v[k] = t4[(size_t)(b * NSEG + g + k) * ROW4 + t];
#pragma unroll
        for (int k = 0; k < 8; ++k)
            if (g + k < s) carry = max4(carry, v[k]);
    }

    const size_t base = ((size_t)b * H + (size_t)s * SH) * ROW4 + t;

    float4 cur[8], nxt[8];
#pragma unroll
    for (int r = 0; r < 8; ++r) cur[r] = x4[base + (size_t)r * ROW4];

#pragma unroll
    for (int g = 0; g < SH; g += 8) {
        if (g + 8 < SH) {
#pragma unroll
            for (int r = 0; r < 8; ++r)
                nxt[r] = x4[base + (size_t)(g + 8 + r) * ROW4];
        }
#pragma unroll
        for (int r = 0; r < 8; ++r) {
            carry = max4(carry, cur[r]);
            o4[base + (size_t)(g + r) * ROW4] = carry;
        }
        if (g + 8 < SH) {
#pragma unroll
            for (int r = 0; r < 8; ++r) cur[r] = nxt[r];
        }
    }
}

// ---------------- fallback: round-11 verified kernel (83 us) --------------
constexpr int SWF = 64;
constexpr int NSTRIP = W / SWF;
constexpr int NBLK = B * NSTRIP;
constexpr int D = 32;
static_assert(H % D == 0, "D must divide H");

__global__ __launch_bounds__(64) void cummax_stream(const float* __restrict__ x,
                                                    float* __restrict__ o) {
    const int sid = blockIdx.x;
    const int b = sid >> 4;
    const int st = sid & (NSTRIP - 1);
    const int lane = threadIdx.x;
    const size_t base = (size_t)b * H * W + (size_t)st * SWF + lane;
    const float* xp = x + base;
    float* op = o + base;
    float carry = -__builtin_inff();
    float buf[D];
#pragma unroll
    for (int r = 0; r < D; ++r) buf[r] = xp[(size_t)r * W];
    int hb = 0;
    for (; hb < H - D; hb += D) {
        const float* xn = xp + (size_t)(hb + D) * W;
        float* on = op + (size_t)hb * W;
#pragma unroll
        for (int r = 0; r < D; ++r) {
            float v = buf[r];
            buf[r] = xn[(size_t)r * W];
            carry = fmaxf(carry, v);
            on[(size_t)r * W] = carry;
        }
    }
    {
        float* on = op + (size_t)hb * W;
#pragma unroll
        for (int r = 0; r < D; ++r) {
            carry = fmaxf(carry, buf[r]);
            on[(size_t)r * W] = carry;
        }
    }
}

extern "C" void kernel_launch(void* const* d_in, const int* in_sizes, int n_in,
                              void* d_out, int out_size, void* d_ws, size_t ws_size,
                              hipStream_t stream) {
    const float* x = (const float*)d_in[0];
    float* out = (float*)d_out;
    if (d_ws != nullptr && ws_size >= AGG_BYTES) {
        float* agg = (float*)d_ws;
        band_colmax<<<NB, 256, 0, stream>>>(x, agg);
        band_apply<<<NB, 256, 0, stream>>>(x, agg, out);
    } else {
        cummax_stream<<<NBLK, 64, 0, stream>>>(x, out);
    }
}